// Round 2
// baseline (204.182 us; speedup 1.0000x reference)
//
#include <hip/hip_runtime.h>
#include <stdint.h>

// Problem constants (Attention_85091892069054): B=2, S=2048, D=1024, H=16, DH=64
// Inputs/outputs are FP32 (reference dtype); internal compute bf16 MFMA + fp32 accum.
#define DIM   1024
#define HEADS 16
#define DHEAD 64
#define SEQ   2048
#define MROWS 4096  // B*S
#define NQ    (MROWS * DIM)   // 4,194,304 elems (q/k/v and per-tensor outputs)
#define NW    (DIM * DIM)     // 1,048,576 elems (weights)

typedef unsigned short u16;
typedef __attribute__((ext_vector_type(8))) short short8;   // 8 bf16 (4 VGPRs) MFMA operand
typedef __attribute__((ext_vector_type(4))) float f32x4;    // MFMA accumulator

static_assert(sizeof(short8) == 16, "short8 must be 16B");

__device__ __forceinline__ u16 f2bf(float f) {
  union { float f; uint32_t u; } x; x.f = f;
  uint32_t r = x.u + 0x7FFFu + ((x.u >> 16) & 1u);  // RNE
  return (u16)(r >> 16);
}

#if __has_builtin(__builtin_amdgcn_global_load_lds)
#define HAVE_GLLDS 1
#else
#define HAVE_GLLDS 0
#endif

// Stage one wave-worth (64 lanes x 16B). global_load_lds: LDS dest is
// wave-uniform base + lane*16 (m97 pattern); global src is per-lane.
__device__ __forceinline__ void stage16(const u16* src, u16* ldsbase, int cb, int lane) {
#if HAVE_GLLDS
  (void)lane;
  __builtin_amdgcn_global_load_lds((const __attribute__((address_space(1))) void*)src,
                                   (__attribute__((address_space(3))) void*)(ldsbase + (size_t)cb * 8),
                                   16, 0, 0);
#else
  *(short8*)(ldsbase + ((size_t)cb + lane) * 8) = *(const short8*)src;
#endif
}

// ---------------------------------------------------------------------------
// fp32 -> bf16 conversion for the 7 big arrays. grid.y selects the array.
// ---------------------------------------------------------------------------
__global__ __launch_bounds__(256)
void cvt_all(const float* __restrict__ q, const float* __restrict__ k, const float* __restrict__ v,
             const float* __restrict__ wq, const float* __restrict__ wk,
             const float* __restrict__ wv, const float* __restrict__ wo,
             u16* __restrict__ qc, u16* __restrict__ kc, u16* __restrict__ vc,
             u16* __restrict__ wqc, u16* __restrict__ wkc, u16* __restrict__ wvc, u16* __restrict__ woc)
{
  const float* s; u16* d; int n;
  switch (blockIdx.y) {
    case 0: s = q;  d = qc;  n = NQ; break;
    case 1: s = k;  d = kc;  n = NQ; break;
    case 2: s = v;  d = vc;  n = NQ; break;
    case 3: s = wq; d = wqc; n = NW; break;
    case 4: s = wk; d = wkc; n = NW; break;
    case 5: s = wv; d = wvc; n = NW; break;
    default: s = wo; d = woc; n = NW; break;
  }
  const int n8 = n >> 3;
  for (int i = blockIdx.x * blockDim.x + threadIdx.x; i < n8; i += gridDim.x * blockDim.x) {
    float4 f0 = ((const float4*)s)[2 * i];
    float4 f1 = ((const float4*)s)[2 * i + 1];
    short8 o;
    o[0] = (short)f2bf(f0.x); o[1] = (short)f2bf(f0.y);
    o[2] = (short)f2bf(f0.z); o[3] = (short)f2bf(f0.w);
    o[4] = (short)f2bf(f1.x); o[5] = (short)f2bf(f1.y);
    o[6] = (short)f2bf(f1.z); o[7] = (short)f2bf(f1.w);
    ((short8*)d)[i] = o;
  }
}

// ---------------------------------------------------------------------------
// NT-GEMM: O[r][c] = (sum_k A[r][k]*W[c][k] + bias[c]) * scale, bf16 in, fp32 acc.
// Tile BM=32*RM x BN=32*RN, BK=32, 256 threads = 4 waves in 2x2.
// MODE 0: write bf16 head-split [B][H][S][DH]; MODE 1: write fp32 flat [M][N].
// blockIdx.z selects one of up to 3 problem triples.
// ---------------------------------------------------------------------------
template <int RM, int RN, int MODE>
__global__ __launch_bounds__(256)
void gemm_nt(const u16* __restrict__ A0, const u16* __restrict__ W0, const float* __restrict__ b0, void* __restrict__ O0, float s0_,
             const u16* __restrict__ A1, const u16* __restrict__ W1, const float* __restrict__ b1, void* __restrict__ O1, float s1_,
             const u16* __restrict__ A2, const u16* __restrict__ W2, const float* __restrict__ b2, void* __restrict__ O2, float s2_)
{
  constexpr int BM = 32 * RM, BN = 32 * RN, BK = 32;
  __shared__ u16 As[BM * BK];
  __shared__ u16 Bs[BN * BK];

  const u16* A = A0; const u16* W = W0; const float* bias = b0; void* O = O0; float oscale = s0_;
  if (blockIdx.z == 1) { A = A1; W = W1; bias = b1; O = O1; oscale = s1_; }
  else if (blockIdx.z == 2) { A = A2; W = W2; bias = b2; O = O2; oscale = s2_; }

  const int tid  = threadIdx.x;
  const int wave = tid >> 6, lane = tid & 63;
  const int g = lane >> 4, cc = lane & 15;
  const int wr = wave >> 1, wc = wave & 1;
  const int m0 = blockIdx.x * BM, n0 = blockIdx.y * BN;

  f32x4 acc[RM][RN];
  for (int m = 0; m < RM; ++m)
    for (int n = 0; n < RN; ++n) acc[m][n] = (f32x4){0.f, 0.f, 0.f, 0.f};

  for (int k0 = 0; k0 < DIM; k0 += BK) {
    __syncthreads();  // prior iter's frag reads done before overwrite
    constexpr int AI = (BM * 4) / 256;   // 16B-chunks per thread for A
    for (int i = 0; i < AI; ++i) {
      int cb = (wave * AI + i) * 64;
      int ch = cb + lane;
      int row = ch >> 2, kc = ch & 3;
      stage16(A + (size_t)(m0 + row) * DIM + k0 + kc * 8, As, cb, lane);
    }
    constexpr int BI = (BN * 4) / 256;
    for (int i = 0; i < BI; ++i) {
      int cb = (wave * BI + i) * 64;
      int ch = cb + lane;
      int row = ch >> 2, kc = ch & 3;
      stage16(W + (size_t)(n0 + row) * DIM + k0 + kc * 8, Bs, cb, lane);
    }
    __syncthreads();  // compiler drains vmcnt/lgkmcnt before barrier

    short8 af[RM], bfr[RN];
    for (int m = 0; m < RM; ++m)
      af[m] = *(const short8*)(As + (size_t)(wr * (16 * RM) + m * 16 + cc) * BK + g * 8);
    for (int n = 0; n < RN; ++n)
      bfr[n] = *(const short8*)(Bs + (size_t)(wc * (16 * RN) + n * 16 + cc) * BK + g * 8);
    for (int m = 0; m < RM; ++m)
      for (int n = 0; n < RN; ++n)
        acc[m][n] = __builtin_amdgcn_mfma_f32_16x16x32_bf16(af[m], bfr[n], acc[m][n], 0, 0, 0);
  }

  // epilogue: C/D layout col=lane&15, row=(lane>>4)*4+reg  [m89-verified]
  for (int n = 0; n < RN; ++n) {
    int col = n0 + wc * (16 * RN) + n * 16 + cc;
    float bv = bias[col];
    for (int m = 0; m < RM; ++m) {
      int rowb = m0 + wr * (16 * RM) + m * 16 + g * 4;
      for (int r = 0; r < 4; ++r) {
        int row = rowb + r;
        float val = (acc[m][n][r] + bv) * oscale;
        if (MODE == 0) {
          int b = row >> 11, s = row & (SEQ - 1);
          int hh = col >> 6, dh = col & 63;
          ((u16*)O)[((((size_t)b * HEADS + hh) * SEQ + s) << 6) + dh] = f2bf(val);
        } else {
          ((float*)O)[(size_t)row * DIM + col] = val;
        }
      }
    }
  }
}

// ---------------------------------------------------------------------------
// Flash attention fwd: Qh,Kh,Vh bf16 [BH=32][S][DH] -> AO bf16 [B][S][D].
// Qh is pre-scaled by DH^-0.5 = 2^-3 (exact). 256 threads = 4 waves; Q-tile
// 128 rows (32/wave, in regs); KV-tile 64. K in XOR-swizzled LDS (128B-row
// bank-conflict fix), V reg-transposed to Vt[dh][kv] (swizzled), P round-trips
// through swizzled LDS as the PV A-operand.
// ---------------------------------------------------------------------------
__global__ __launch_bounds__(256)
void attn_fwd(const u16* __restrict__ Qb, const u16* __restrict__ Kb,
              const u16* __restrict__ Vb, u16* __restrict__ AO)
{
  const int bh = blockIdx.y;
  const int q0 = blockIdx.x * 128;
  const int tid = threadIdx.x, wave = tid >> 6, lane = tid & 63;
  const int g = lane >> 4, cc = lane & 15;
  const size_t base = (size_t)bh * SEQ * DHEAD;
  const u16* Qg = Qb + base;
  const u16* Kg = Kb + base;
  const u16* Vg = Vb + base;

  __shared__ u16 Ks[64 * 64];    // 8KB,  swizzled [kv][dh]
  __shared__ u16 Vts[64 * 64];   // 8KB,  swizzled [dh][kv]
  __shared__ u16 Ps[128 * 64];   // 16KB, swizzled [q][kv]

  short8 qf[2][2];
  for (int m = 0; m < 2; ++m)
    for (int ks = 0; ks < 2; ++ks)
      qf[m][ks] = *(const short8*)(Qg + (size_t)(q0 + wave * 32 + m * 16 + cc) * DHEAD + ks * 32 + g * 8);

  f32x4 o[2][4];
  for (int m = 0; m < 2; ++m)
    for (int n = 0; n < 4; ++n) o[m][n] = (f32x4){0.f, 0.f, 0.f, 0.f};
  float mrun[2][4], lrun[2][4];
  for (int m = 0; m < 2; ++m)
    for (int r = 0; r < 4; ++r) { mrun[m][r] = -1e30f; lrun[m][r] = 0.f; }

  for (int t = 0; t < SEQ / 64; ++t) {
    const int kv0 = t * 64;
    __syncthreads();  // prior iter done with Ks/Vts

    // stage K (64x64): linear LDS dest, XOR-swizzle folded into global source
    for (int i = 0; i < 2; ++i) {
      int cb = (wave * 2 + i) * 64;
      int ch = cb + lane;
      int row = ch >> 3;
      int lkc = (ch & 7) ^ (row & 7);  // logical chunk staged at this physical slot
      stage16(Kg + (size_t)(kv0 + row) * DHEAD + lkc * 8, Ks, cb, lane);
    }
    // stage V transposed: Vt[dh][kv] = V[kv][dh], swizzled, pairwise b32 writes
    {
      int rp = tid & 31, c8 = tid >> 5;
      const short8 v0 = *(const short8*)(Vg + (size_t)(kv0 + 2 * rp) * DHEAD + c8 * 8);
      const short8 v1 = *(const short8*)(Vg + (size_t)(kv0 + 2 * rp + 1) * DHEAD + c8 * 8);
      for (int j = 0; j < 8; ++j) {
        uint32_t row = c8 * 8 + j;
        uint32_t byte = (row * 128 + rp * 4) ^ ((row & 7) << 4);
        *(uint32_t*)((char*)Vts + byte) =
            (uint32_t)(u16)v0[j] | ((uint32_t)(u16)v1[j] << 16);
      }
    }
    __syncthreads();

    // S = Q K^T (B-operand = K rows, contiguous in dh)
    short8 kf[4][2];
    for (int f = 0; f < 4; ++f)
      for (int ks = 0; ks < 2; ++ks) {
        uint32_t row = f * 16 + cc;
        uint32_t byte = (row * 128 + (ks * 32 + g * 8) * 2) ^ ((row & 7) << 4);
        kf[f][ks] = *(const short8*)((const char*)Ks + byte);
      }
    f32x4 sc[2][4];
    for (int m = 0; m < 2; ++m)
      for (int f = 0; f < 4; ++f) sc[m][f] = (f32x4){0.f, 0.f, 0.f, 0.f};
    for (int m = 0; m < 2; ++m)
      for (int f = 0; f < 4; ++f)
        for (int ks = 0; ks < 2; ++ks)
          sc[m][f] = __builtin_amdgcn_mfma_f32_16x16x32_bf16(qf[m][ks], kf[f][ks], sc[m][f], 0, 0, 0);

    // online softmax; C-frag row = g*4+r is per-lane, stats reduce over cc
    for (int m = 0; m < 2; ++m) {
      float alpha[4];
      for (int r = 0; r < 4; ++r) {
        float mx = fmaxf(fmaxf(sc[m][0][r], sc[m][1][r]), fmaxf(sc[m][2][r], sc[m][3][r]));
        mx = fmaxf(mx, __shfl_xor(mx, 1));
        mx = fmaxf(mx, __shfl_xor(mx, 2));
        mx = fmaxf(mx, __shfl_xor(mx, 4));
        mx = fmaxf(mx, __shfl_xor(mx, 8));
        float mn = fmaxf(mrun[m][r], mx);
        alpha[r] = __expf(mrun[m][r] - mn);
        mrun[m][r] = mn;
      }
      float rs[4] = {0.f, 0.f, 0.f, 0.f};
      for (int f = 0; f < 4; ++f)
        for (int r = 0; r < 4; ++r) {
          float p = __expf(sc[m][f][r] - mrun[m][r]);
          sc[m][f][r] = p;
          rs[r] += p;
        }
      for (int r = 0; r < 4; ++r) {
        float s = rs[r];
        s += __shfl_xor(s, 1);
        s += __shfl_xor(s, 2);
        s += __shfl_xor(s, 4);
        s += __shfl_xor(s, 8);
        lrun[m][r] = lrun[m][r] * alpha[r] + s;
      }
      for (int n = 0; n < 4; ++n)
        for (int r = 0; r < 4; ++r) o[m][n][r] *= alpha[r];
      // P -> LDS (bf16, C-layout coords), swizzled
      for (int f = 0; f < 4; ++f)
        for (int r = 0; r < 4; ++r) {
          uint32_t qrow = wave * 32 + m * 16 + g * 4 + r;
          uint32_t byte = (qrow * 128 + (f * 16 + cc) * 2) ^ ((qrow & 7) << 4);
          *(u16*)((char*)Ps + byte) = f2bf(sc[m][f][r]);
        }
    }
    // cross-lane P write -> read: DS ops per wave complete in order; drain anyway
    asm volatile("s_waitcnt lgkmcnt(0)" ::: "memory");

    // O += P V  (A = P rows, B = Vt rows = V columns)
    short8 pf[2][2], vf[4][2];
    for (int m = 0; m < 2; ++m)
      for (int ks = 0; ks < 2; ++ks) {
        uint32_t qrow = wave * 32 + m * 16 + cc;
        uint32_t byte = (qrow * 128 + (ks * 32 + g * 8) * 2) ^ ((qrow & 7) << 4);
        pf[m][ks] = *(const short8*)((const char*)Ps + byte);
      }
    for (int n = 0; n < 4; ++n)
      for (int ks = 0; ks < 2; ++ks) {
        uint32_t dh = n * 16 + cc;
        uint32_t byte = (dh * 128 + (ks * 32 + g * 8) * 2) ^ ((dh & 7) << 4);
        vf[n][ks] = *(const short8*)((const char*)Vts + byte);
      }
    for (int m = 0; m < 2; ++m)
      for (int n = 0; n < 4; ++n)
        for (int ks = 0; ks < 2; ++ks)
          o[m][n] = __builtin_amdgcn_mfma_f32_16x16x32_bf16(pf[m][ks], vf[n][ks], o[m][n], 0, 0, 0);
  }

  // epilogue -> AO [B][S][D] (head-merged), bf16
  const int b = bh >> 4, h = bh & 15;
  for (int m = 0; m < 2; ++m)
    for (int r = 0; r < 4; ++r) {
      float inv = 1.0f / lrun[m][r];
      int srow = q0 + wave * 32 + m * 16 + g * 4 + r;
      for (int n = 0; n < 4; ++n) {
        int col = h * 64 + n * 16 + cc;
        AO[((size_t)b * SEQ + srow) * DIM + col] = f2bf(o[m][n][r] * inv);
      }
    }
}

// ---------------------------------------------------------------------------
extern "C" void kernel_launch(void* const* d_in, const int* in_sizes, int n_in,
                              void* d_out, int out_size, void* d_ws, size_t ws_size,
                              hipStream_t stream)
{
  const float* q  = (const float*)d_in[0];
  const float* k  = (const float*)d_in[1];
  const float* v  = (const float*)d_in[2];
  const float* Wq = (const float*)d_in[3];
  const float* bq = (const float*)d_in[4];
  const float* Wk = (const float*)d_in[5];
  const float* bk = (const float*)d_in[6];
  const float* Wv = (const float*)d_in[7];
  const float* bv = (const float*)d_in[8];
  const float* Wo = (const float*)d_in[9];
  const float* bo = (const float*)d_in[10];
  float* out = (float*)d_out;

  // d_ws layout (u16 elems): qc,kc,vc [NQ], wqc..woc [NW], Qh,Kh,Vh [NQ], AO [NQ]
  u16* qc  = (u16*)d_ws;
  u16* kc  = qc  + NQ;
  u16* vc  = kc  + NQ;
  u16* wqc = vc  + NQ;
  u16* wkc = wqc + NW;
  u16* wvc = wkc + NW;
  u16* woc = wvc + NW;
  u16* Qh  = woc + NW;
  u16* Kh  = Qh  + NQ;
  u16* Vh  = Kh  + NQ;
  u16* AO  = Vh  + NQ;   // total 64 MB

  dim3 blk(256);
  // fp32 -> bf16 for q,k,v,Wq,Wk,Wv,Wo
  hipLaunchKernelGGL(cvt_all, dim3(512, 7, 1), blk, 0, stream,
                     q, k, v, Wq, Wk, Wv, Wo, qc, kc, vc, wqc, wkc, wvc, woc);
  // Q/K/V projections batched via grid.z (Q pre-scaled by 2^-3 exactly)
  hipLaunchKernelGGL((gemm_nt<4, 4, 0>), dim3(MROWS / 128, DIM / 128, 3), blk, 0, stream,
                     qc, wqc, bq, (void*)Qh, 0.125f,
                     kc, wkc, bk, (void*)Kh, 1.0f,
                     vc, wvc, bv, (void*)Vh, 1.0f);
  // attention: 16 q-tiles x 32 (b,h)
  hipLaunchKernelGGL(attn_fwd, dim3(SEQ / 128, 32, 1), blk, 0, stream, Qh, Kh, Vh, AO);
  // output projection -> fp32 d_out
  hipLaunchKernelGGL((gemm_nt<2, 4, 1>), dim3(MROWS / 64, DIM / 128, 1), blk, 0, stream,
                     AO, woc, bo, (void*)out, 1.0f,
                     nullptr, nullptr, nullptr, nullptr, 1.0f,
                     nullptr, nullptr, nullptr, nullptr, 1.0f);
}

// Round 3
// 155.920 us; speedup vs baseline: 1.3095x; 1.3095x over previous
//
#include <hip/hip_runtime.h>
#include <stdint.h>

// Problem constants (Attention_85091892069054): B=2, S=2048, D=1024, H=16, DH=64
// Inputs/outputs FP32; internal bf16 MFMA + fp32 accum.
#define DIM   1024
#define HEADS 16
#define DHEAD 64
#define SEQ   2048
#define MROWS 4096  // B*S
#define NQ    (MROWS * DIM)
#define NW    (DIM * DIM)

typedef unsigned short u16;
typedef __attribute__((ext_vector_type(8))) short short8;    // 8 bf16
typedef __attribute__((ext_vector_type(4))) float f32x4;     // 16x16 accum
typedef __attribute__((ext_vector_type(16))) float f32x16;   // 32x32 accum

static_assert(sizeof(short8) == 16, "short8 must be 16B");

__device__ __forceinline__ float bf2f(u16 u) {
  union { float f; uint32_t u; } x; x.u = ((uint32_t)u) << 16; return x.f;
}
__device__ __forceinline__ u16 f2bf(float f) {
  union { float f; uint32_t u; } x; x.f = f;
  uint32_t r = x.u + 0x7FFFu + ((x.u >> 16) & 1u);  // RNE
  return (u16)(r >> 16);
}
// packed f32x2 -> bf16x2 (RNE), lo -> [15:0], hi -> [31:16]
__device__ __forceinline__ uint32_t cvtpk(float lo, float hi) {
  uint32_t r;
  asm("v_cvt_pk_bf16_f32 %0, %1, %2" : "=v"(r) : "v"(lo), "v"(hi));
  return r;
}

#if __has_builtin(__builtin_amdgcn_global_load_lds)
#define HAVE_GLLDS 1
#else
#define HAVE_GLLDS 0
#endif

__device__ __forceinline__ void stage16(const u16* src, u16* ldsbase, int cb, int lane) {
#if HAVE_GLLDS
  (void)lane;
  __builtin_amdgcn_global_load_lds((const __attribute__((address_space(1))) void*)src,
                                   (__attribute__((address_space(3))) void*)(ldsbase + (size_t)cb * 8),
                                   16, 0, 0);
#else
  *(short8*)(ldsbase + ((size_t)cb + lane) * 8) = *(const short8*)src;
#endif
}

// ---------------------------------------------------------------------------
// fp32 -> bf16 conversion for the 7 big arrays. grid.y selects the array.
// ---------------------------------------------------------------------------
__global__ __launch_bounds__(256)
void cvt_all(const float* __restrict__ q, const float* __restrict__ k, const float* __restrict__ v,
             const float* __restrict__ wq, const float* __restrict__ wk,
             const float* __restrict__ wv, const float* __restrict__ wo,
             u16* __restrict__ qc, u16* __restrict__ kc, u16* __restrict__ vc,
             u16* __restrict__ wqc, u16* __restrict__ wkc, u16* __restrict__ wvc, u16* __restrict__ woc)
{
  const float* s; u16* d; int n;
  switch (blockIdx.y) {
    case 0: s = q;  d = qc;  n = NQ; break;
    case 1: s = k;  d = kc;  n = NQ; break;
    case 2: s = v;  d = vc;  n = NQ; break;
    case 3: s = wq; d = wqc; n = NW; break;
    case 4: s = wk; d = wkc; n = NW; break;
    case 5: s = wv; d = wvc; n = NW; break;
    default: s = wo; d = woc; n = NW; break;
  }
  const int n8 = n >> 3;
  for (int i = blockIdx.x * blockDim.x + threadIdx.x; i < n8; i += gridDim.x * blockDim.x) {
    float4 f0 = ((const float4*)s)[2 * i];
    float4 f1 = ((const float4*)s)[2 * i + 1];
    short8 o;
    o[0] = (short)f2bf(f0.x); o[1] = (short)f2bf(f0.y);
    o[2] = (short)f2bf(f0.z); o[3] = (short)f2bf(f0.w);
    o[4] = (short)f2bf(f1.x); o[5] = (short)f2bf(f1.y);
    o[6] = (short)f2bf(f1.z); o[7] = (short)f2bf(f1.w);
    ((short8*)d)[i] = o;
  }
}

// ---------------------------------------------------------------------------
// NT-GEMM (unchanged from round 2, proven): O = (A*W^T + bias) * scale.
// MODE 0: bf16 head-split out; MODE 1: fp32 flat out.
// ---------------------------------------------------------------------------
template <int RM, int RN, int MODE>
__global__ __launch_bounds__(256)
void gemm_nt(const u16* __restrict__ A0, const u16* __restrict__ W0, const float* __restrict__ b0, void* __restrict__ O0, float s0_,
             const u16* __restrict__ A1, const u16* __restrict__ W1, const float* __restrict__ b1, void* __restrict__ O1, float s1_,
             const u16* __restrict__ A2, const u16* __restrict__ W2, const float* __restrict__ b2, void* __restrict__ O2, float s2_)
{
  constexpr int BM = 32 * RM, BN = 32 * RN, BK = 32;
  __shared__ u16 As[BM * BK];
  __shared__ u16 Bs[BN * BK];

  const u16* A = A0; const u16* W = W0; const float* bias = b0; void* O = O0; float oscale = s0_;
  if (blockIdx.z == 1) { A = A1; W = W1; bias = b1; O = O1; oscale = s1_; }
  else if (blockIdx.z == 2) { A = A2; W = W2; bias = b2; O = O2; oscale = s2_; }

  const int tid  = threadIdx.x;
  const int wave = tid >> 6, lane = tid & 63;
  const int g = lane >> 4, cc = lane & 15;
  const int wr = wave >> 1, wc = wave & 1;
  const int m0 = blockIdx.x * BM, n0 = blockIdx.y * BN;

  f32x4 acc[RM][RN];
  for (int m = 0; m < RM; ++m)
    for (int n = 0; n < RN; ++n) acc[m][n] = (f32x4){0.f, 0.f, 0.f, 0.f};

  for (int k0 = 0; k0 < DIM; k0 += BK) {
    __syncthreads();
    constexpr int AI = (BM * 4) / 256;
    for (int i = 0; i < AI; ++i) {
      int cb = (wave * AI + i) * 64;
      int ch = cb + lane;
      int row = ch >> 2, kc = ch & 3;
      stage16(A + (size_t)(m0 + row) * DIM + k0 + kc * 8, As, cb, lane);
    }
    constexpr int BI = (BN * 4) / 256;
    for (int i = 0; i < BI; ++i) {
      int cb = (wave * BI + i) * 64;
      int ch = cb + lane;
      int row = ch >> 2, kc = ch & 3;
      stage16(W + (size_t)(n0 + row) * DIM + k0 + kc * 8, Bs, cb, lane);
    }
    __syncthreads();

    short8 af[RM], bfr[RN];
    for (int m = 0; m < RM; ++m)
      af[m] = *(const short8*)(As + (size_t)(wr * (16 * RM) + m * 16 + cc) * BK + g * 8);
    for (int n = 0; n < RN; ++n)
      bfr[n] = *(const short8*)(Bs + (size_t)(wc * (16 * RN) + n * 16 + cc) * BK + g * 8);
    for (int m = 0; m < RM; ++m)
      for (int n = 0; n < RN; ++n)
        acc[m][n] = __builtin_amdgcn_mfma_f32_16x16x32_bf16(af[m], bfr[n], acc[m][n], 0, 0, 0);
  }

  for (int n = 0; n < RN; ++n) {
    int col = n0 + wc * (16 * RN) + n * 16 + cc;
    float bv = bias[col];
    for (int m = 0; m < RM; ++m) {
      int rowb = m0 + wr * (16 * RM) + m * 16 + g * 4;
      for (int r = 0; r < 4; ++r) {
        int row = rowb + r;
        float val = (acc[m][n][r] + bv) * oscale;
        if (MODE == 0) {
          int b = row >> 11, s = row & (SEQ - 1);
          int hh = col >> 6, dh = col & 63;
          ((u16*)O)[((((size_t)b * HEADS + hh) * SEQ + s) << 6) + dh] = f2bf(val);
        } else {
          ((float*)O)[(size_t)row * DIM + col] = val;
        }
      }
    }
  }
}

// ---------------------------------------------------------------------------
// Flash attention fwd, swapped-QK^T (T12 structure), 32x32x16 MFMA, KV-split=2.
// Per block: 4 waves x 32 q-rows = 128 q-rows; kv range [split*1024, +1024).
// S^T = K*Q^T -> lane owns q-col (lane&31), 16 kv regs (+ partner lane^32).
// Softmax in-register; P repacked to PV B-frag via cvt_pk + shfl_xor(32).
// PV: O^T = V^T * P^T -> O col = q = lane&31, rescale is lane-local.
// Writes UNNORMALIZED O~ (bf16) + (m, l) stats; combine kernel merges splits.
// ---------------------------------------------------------------------------
__global__ __launch_bounds__(256)
void attn_fwd2(const u16* __restrict__ Qb, const u16* __restrict__ Kb,
               const u16* __restrict__ Vb, u16* __restrict__ Opart,
               float2* __restrict__ stats)
{
  // XCD-aware bijective swizzle: 1024 blocks = 8 XCDs x 128 contiguous logical
  uint32_t lid = blockIdx.x;
  uint32_t logical = (lid & 7) * 128 + (lid >> 3);
  const int qt    = logical & 15;
  const int bh    = (logical >> 4) & 31;
  const int split = logical >> 9;

  const int q0 = qt * 128;
  const int kvbase = split * (SEQ / 2);
  const int tid = threadIdx.x, wave = tid >> 6, lane = tid & 63;
  const int l31 = lane & 31, hi = lane >> 5;

  const size_t base = (size_t)bh * SEQ * DHEAD;
  const u16* Qg = Qb + base;
  const u16* Kg = Kb + base;
  const u16* Vg = Vb + base;

  __shared__ u16 Ks[64 * 64];    // 8KB, swizzled [kv][dh], 128B rows
  __shared__ u16 Vts[64 * 64];   // 8KB, swizzled [dh][kv], 128B rows

  // Q B-frag: lane holds col q = l31, k(=dh) slices ks*16 + hi*8 .. +8
  short8 qf[4];
  {
    const u16* qrow = Qg + (size_t)(q0 + wave * 32 + l31) * DHEAD + hi * 8;
    for (int ks = 0; ks < 4; ++ks)
      qf[ks] = *(const short8*)(qrow + ks * 16);
  }

  f32x16 o0, o1;
  for (int r = 0; r < 16; ++r) { o0[r] = 0.f; o1[r] = 0.f; }
  float m = -1e30f, l = 0.f;

  for (int t = 0; t < (SEQ / 2) / 64; ++t) {
    const int kv0 = kvbase + t * 64;
    __syncthreads();  // prior iter done with Ks/Vts
    // stage K (64x64): linear LDS dest, swizzle folded into global source
    for (int i = 0; i < 2; ++i) {
      int cb = (wave * 2 + i) * 64;
      int ch = cb + lane;
      int row = ch >> 3;
      int lkc = (ch & 7) ^ (row & 7);
      stage16(Kg + (size_t)(kv0 + row) * DHEAD + lkc * 8, Ks, cb, lane);
    }
    // stage V transposed: Vt[dh][kv], swizzled, pairwise b32 writes
    {
      int rp = tid & 31, c8 = tid >> 5;
      const short8 v0 = *(const short8*)(Vg + (size_t)(kv0 + 2 * rp) * DHEAD + c8 * 8);
      const short8 v1 = *(const short8*)(Vg + (size_t)(kv0 + 2 * rp + 1) * DHEAD + c8 * 8);
      for (int j = 0; j < 8; ++j) {
        uint32_t row = c8 * 8 + j;
        uint32_t byte = (row * 128 + rp * 4) ^ ((row & 7) << 4);
        *(uint32_t*)((char*)Vts + byte) =
            (uint32_t)(u16)v0[j] | ((uint32_t)(u16)v1[j] << 16);
      }
    }
    __syncthreads();

    for (int ksb = 0; ksb < 2; ++ksb) {   // two 32-kv sub-tiles
      // S^T = K * Q^T over dh=64 (4 mfma k=16)
      f32x16 s;
      for (int r = 0; r < 16; ++r) s[r] = 0.f;
      {
        uint32_t row = ksb * 32 + l31;
        uint32_t rb = row * 128, sw = (row & 7) << 4;
        for (int ks = 0; ks < 4; ++ks) {
          short8 kf = *(const short8*)((const char*)Ks + ((rb + ks * 32 + hi * 16) ^ sw));
          s = __builtin_amdgcn_mfma_f32_32x32x16_bf16(kf, qf[ks], s, 0, 0, 0);
        }
      }
      // online softmax: lane owns q = l31; 16 kv here + 16 on partner lane
      float pmax = s[0];
      for (int r = 1; r < 16; ++r) pmax = fmaxf(pmax, s[r]);
      pmax = fmaxf(pmax, __shfl_xor(pmax, 32));
      // T13 defer-max: skip rescale while growth bounded by e^8
      if (!__all(pmax <= m + 8.0f)) {
        float mn = fmaxf(m, pmax);
        float alpha = __expf(m - mn);
        m = mn;
        l *= alpha;
        for (int r = 0; r < 16; ++r) { o0[r] *= alpha; o1[r] *= alpha; }
      }
      float p[16], rsum = 0.f;
      for (int r = 0; r < 16; ++r) { p[r] = __expf(s[r] - m); rsum += p[r]; }
      rsum += __shfl_xor(rsum, 32);
      l += rsum;

      // repack P -> PV B-frags. Reg r holds kv_r = (r&3)+8*(r>>2)+4*hi.
      // words: a={4hi,4hi+1} b={4hi+2,+3} c={8+4hi,..} d  e,f,g,h = +16.
      uint32_t a  = cvtpk(p[0], p[1]),   b  = cvtpk(p[2], p[3]);
      uint32_t c  = cvtpk(p[4], p[5]),   d  = cvtpk(p[6], p[7]);
      uint32_t e  = cvtpk(p[8], p[9]),   f  = cvtpk(p[10], p[11]);
      uint32_t g2 = cvtpk(p[12], p[13]), h2 = cvtpk(p[14], p[15]);
      uint32_t pa = __shfl_xor((int)a, 32),  pb = __shfl_xor((int)b, 32);
      uint32_t pc = __shfl_xor((int)c, 32),  pd = __shfl_xor((int)d, 32);
      uint32_t pe = __shfl_xor((int)e, 32),  pf2 = __shfl_xor((int)f, 32);
      uint32_t pg = __shfl_xor((int)g2, 32), ph = __shfl_xor((int)h2, 32);
      short8 pfrag[2];
      {
        union { uint32_t w[4]; short8 s8; } u0, u1;
        u0.w[0] = hi ? pc : a;  u0.w[1] = hi ? pd : b;
        u0.w[2] = hi ? c  : pa; u0.w[3] = hi ? d  : pb;
        u1.w[0] = hi ? pg : e;  u1.w[1] = hi ? ph : f;
        u1.w[2] = hi ? g2 : pe; u1.w[3] = hi ? h2 : pf2;
        pfrag[0] = u0.s8; pfrag[1] = u1.s8;
      }
      // PV: O^T += V^T P^T  (A = Vt rows = V columns; B = P^T in regs)
      for (int ks16 = 0; ks16 < 2; ++ks16) {
        uint32_t kvb = (uint32_t)(ksb * 64 + ks16 * 32 + hi * 16);  // byte col
        {
          uint32_t row = l31;
          short8 vf = *(const short8*)((const char*)Vts + ((row * 128 + kvb) ^ ((row & 7) << 4)));
          o0 = __builtin_amdgcn_mfma_f32_32x32x16_bf16(vf, pfrag[ks16], o0, 0, 0, 0);
        }
        {
          uint32_t row = 32 + l31;
          short8 vf = *(const short8*)((const char*)Vts + ((row * 128 + kvb) ^ ((row & 7) << 4)));
          o1 = __builtin_amdgcn_mfma_f32_32x32x16_bf16(vf, pfrag[ks16], o1, 0, 0, 0);
        }
      }
    }
  }

  // epilogue: unnormalized O~ (bf16) + (m,l). O^T row dh = db*32 + 8*gq + 4*hi + j
  const int q = q0 + wave * 32 + l31;
  u16* orow = Opart + (((size_t)split * 32 + bh) * SEQ + q) * DHEAD;
  for (int db = 0; db < 2; ++db) {
    const f32x16& o = db ? o1 : o0;
    for (int gq = 0; gq < 4; ++gq) {
      int dh = db * 32 + gq * 8 + hi * 4;
      ushort4 w;
      w.x = f2bf(o[gq * 4 + 0]); w.y = f2bf(o[gq * 4 + 1]);
      w.z = f2bf(o[gq * 4 + 2]); w.w = f2bf(o[gq * 4 + 3]);
      *(ushort4*)(orow + dh) = w;
    }
  }
  if (hi == 0)
    stats[((size_t)split * 32 + bh) * SEQ + q] = make_float2(m, l);
}

// ---------------------------------------------------------------------------
// Combine the 2 KV-split partials -> AO bf16 [B][S][D] (head-merged).
// ---------------------------------------------------------------------------
__global__ __launch_bounds__(256)
void attn_combine(const u16* __restrict__ Opart, const float2* __restrict__ stats,
                  u16* __restrict__ AO)
{
  int idx = blockIdx.x * blockDim.x + threadIdx.x;  // 32*2048*8 chunks of 8 dh
  if (idx >= 32 * SEQ * 8) return;
  int c8 = idx & 7;
  int q  = (idx >> 3) & (SEQ - 1);
  int bh = idx >> 14;
  float2 s0 = stats[((size_t)bh) * SEQ + q];
  float2 s1 = stats[((size_t)32 + bh) * SEQ + q];
  float M = fmaxf(s0.x, s1.x);
  float w0 = __expf(s0.x - M), w1 = __expf(s1.x - M);
  float inv = 1.f / (w0 * s0.y + w1 * s1.y);
  const short8 a = *(const short8*)(Opart + (((size_t)bh) * SEQ + q) * DHEAD + c8 * 8);
  const short8 b = *(const short8*)(Opart + (((size_t)32 + bh) * SEQ + q) * DHEAD + c8 * 8);
  int bb = bh >> 4, h = bh & 15;
  short8 r;
  for (int j = 0; j < 8; ++j)
    r[j] = (short)f2bf((w0 * bf2f((u16)a[j]) + w1 * bf2f((u16)b[j])) * inv);
  *(short8*)(AO + ((size_t)bb * SEQ + q) * DIM + h * 64 + c8 * 8) = r;
}

// ---------------------------------------------------------------------------
extern "C" void kernel_launch(void* const* d_in, const int* in_sizes, int n_in,
                              void* d_out, int out_size, void* d_ws, size_t ws_size,
                              hipStream_t stream)
{
  const float* q  = (const float*)d_in[0];
  const float* k  = (const float*)d_in[1];
  const float* v  = (const float*)d_in[2];
  const float* Wq = (const float*)d_in[3];
  const float* bq = (const float*)d_in[4];
  const float* Wk = (const float*)d_in[5];
  const float* bk = (const float*)d_in[6];
  const float* Wv = (const float*)d_in[7];
  const float* bv = (const float*)d_in[8];
  const float* Wo = (const float*)d_in[9];
  const float* bo = (const float*)d_in[10];
  float* out = (float*)d_out;

  // d_ws (u16 elems): [qc kc vc][wqc wkc wvc woc][Qh Kh Vh][AO]
  // After gemm1, qc/kc/vc are dead -> attn partials (Opart 16.8MB + stats 1MB)
  // alias that region (Qh starts at 33.5MB, no overlap).
  u16* qc  = (u16*)d_ws;
  u16* kc  = qc  + NQ;
  u16* vc  = kc  + NQ;
  u16* wqc = vc  + NQ;
  u16* wkc = wqc + NW;
  u16* wvc = wkc + NW;
  u16* woc = wvc + NW;
  u16* Qh  = woc + NW;
  u16* Kh  = Qh  + NQ;
  u16* Vh  = Kh  + NQ;
  u16* AO  = Vh  + NQ;

  u16*    Opart = (u16*)d_ws;                                   // [2][32][S][64] bf16
  float2* stats = (float2*)((u16*)d_ws + (size_t)2 * 32 * SEQ * DHEAD);  // [2][32][S]

  dim3 blk(256);
  hipLaunchKernelGGL(cvt_all, dim3(512, 7, 1), blk, 0, stream,
                     q, k, v, Wq, Wk, Wv, Wo, qc, kc, vc, wqc, wkc, wvc, woc);
  hipLaunchKernelGGL((gemm_nt<4, 4, 0>), dim3(MROWS / 128, DIM / 128, 3), blk, 0, stream,
                     qc, wqc, bq, (void*)Qh, 0.125f,
                     kc, wkc, bk, (void*)Kh, 1.0f,
                     vc, wvc, bv, (void*)Vh, 1.0f);
  hipLaunchKernelGGL(attn_fwd2, dim3(1024, 1, 1), blk, 0, stream, Qh, Kh, Vh, Opart, stats);
  hipLaunchKernelGGL(attn_combine, dim3((32 * SEQ * 8) / 256, 1, 1), blk, 0, stream,
                     Opart, stats, AO);
  hipLaunchKernelGGL((gemm_nt<2, 4, 1>), dim3(MROWS / 64, DIM / 128, 1), blk, 0, stream,
                     AO, woc, bo, (void*)out, 1.0f,
                     nullptr, nullptr, nullptr, nullptr, 1.0f,
                     nullptr, nullptr, nullptr, nullptr, 1.0f);
}